// Round 17
// baseline (215.831 us; speedup 1.0000x reference)
//
#include <hip/hip_runtime.h>
#include <stdint.h>

typedef unsigned short ushort_t;
typedef __attribute__((ext_vector_type(8))) short bf16x8;   // 8 bf16 = 4 VGPRs
typedef __attribute__((ext_vector_type(4))) float f32x4;
typedef __attribute__((ext_vector_type(16))) float f32x16;
typedef __attribute__((ext_vector_type(4))) unsigned int u32x4;

__device__ __forceinline__ ushort_t f2bf(float f) {
  union { float f; unsigned u; } v; v.f = f;
  unsigned r = v.u + 0x7fffu + ((v.u >> 16) & 1u);
  return (ushort_t)(r >> 16);
}
__device__ __forceinline__ unsigned bfbits(float f) {
  union { float f; unsigned u; } v; v.f = f; return v.u;
}
// pack two floats' bf16 truncations: [hi.bf16 : lo.bf16]
__device__ __forceinline__ unsigned pack_trunc(float lo, float hi) {
#if __has_builtin(__builtin_amdgcn_perm)
  return __builtin_amdgcn_perm(bfbits(hi), bfbits(lo), 0x07060302u);
#else
  return (bfbits(lo) >> 16) | (bfbits(hi) & 0xffff0000u);
#endif
}
__device__ __forceinline__ unsigned pack_rn(float lo, float hi) {
  return (unsigned)f2bf(lo) | ((unsigned)f2bf(hi) << 16);
}
// v_permlane32_swap_b32: a.hi32lanes <-> b.lo32lanes (both updated)
__device__ __forceinline__ void swap32(unsigned &a, unsigned &b) {
#if __has_builtin(__builtin_amdgcn_permlane32_swap)
  auto r = __builtin_amdgcn_permlane32_swap(a, b, false, false);
  a = r[0]; b = r[1];
#else
  asm volatile("v_permlane32_swap_b32 %0, %1" : "+v"(a), "+v"(b));
#endif
}
// raw v_exp_f32 (1 instr): libm exp2f expands to a multi-instr fixup
// sequence without fast-math; our inputs are bounded so raw HW op is exact.
__device__ __forceinline__ float fast_exp2(float x) {
#if __has_builtin(__builtin_amdgcn_exp2f)
  return __builtin_amdgcn_exp2f(x);
#else
  float r; asm("v_exp_f32 %0, %1" : "=v"(r) : "v"(x)); return r;
#endif
}
// sched_group_barrier: compile-time instruction-interleave directive
#if __has_builtin(__builtin_amdgcn_sched_group_barrier)
#define SGB(mask, n) __builtin_amdgcn_sched_group_barrier(mask, n, 0)
#else
#define SGB(mask, n)
#endif

#define SCALE_Q 0.18033688011112042f   /* 0.125 * log2(e) */
#define EXP_BIAS 23.083109273961734f   /* 16 * log2(e) */

// ---------- GroupNorm stats stage 1: 256 blocks x 16384 floats -------------
__global__ __launch_bounds__(256)
void gn_stats1(const float* __restrict__ x, float2* __restrict__ partial) {
  int blk = blockIdx.x, tid = threadIdx.x;
  const float* base = x + (size_t)blk * 16384;
  float s = 0.f, ss = 0.f;
  for (int i = tid * 4; i < 16384; i += 1024) {
    float4 v = *(const float4*)(base + i);
    s  += v.x + v.y + v.z + v.w;
    ss += v.x*v.x + v.y*v.y + v.z*v.z + v.w*v.w;
  }
  __shared__ float rs[256], rss[256];
  rs[tid] = s; rss[tid] = ss;
  __syncthreads();
  for (int off = 128; off > 0; off >>= 1) {
    if (tid < off) { rs[tid] += rs[tid+off]; rss[tid] += rss[tid+off]; }
    __syncthreads();
  }
  if (tid == 0) partial[blk] = make_float2(rs[0], rss[0]);
}

// -- normalize+transpose: x[b][c][n] -> xn_t[(b-b0)*4096+n][c] (bf16 chunk) -
// gn_stats2 folded in: each block reduces its group's 8 partials itself.
__global__ __launch_bounds__(256)
void gn_apply_t(const float* __restrict__ x, const float2* __restrict__ partial,
                const float* __restrict__ gamma, const float* __restrict__ beta,
                ushort_t* __restrict__ xn_t, int b0) {
  int blk = blockIdx.x;            // nb*128 = bl x nt(16) x ct(8)
  int tid = threadIdx.x;
  int ct = blk & 7;
  int nt = (blk >> 3) & 15;
  int bl = blk >> 7;               // local batch in chunk
  int b  = b0 + bl;                // global batch
  int c0 = ct * 32;                // one 32-ch group per tile (group == ct)
  float s = 0.f, ss = 0.f;
  #pragma unroll
  for (int kk = 0; kk < 8; kk++) {
    float2 p = partial[(b*8 + ct)*8 + kk];
    s += p.x; ss += p.y;
  }
  float mean = s * (1.f/131072.f);
  float rstd = rsqrtf(ss * (1.f/131072.f) - mean*mean + 1e-5f);
  __shared__ ushort_t Ls[32][264];
  for (int idx = tid; idx < 32*64; idx += 256) {
    int cc = idx >> 6, seg = idx & 63;
    float ga = gamma[c0+cc], be = beta[c0+cc];
    float a = rstd * ga;
    float bb = be - mean * a;
    float4 v = *(const float4*)(x + ((size_t)(b*256 + c0 + cc))*4096 + nt*256 + seg*4);
    ushort4 t4 = make_ushort4(f2bf(v.x*a+bb), f2bf(v.y*a+bb), f2bf(v.z*a+bb), f2bf(v.w*a+bb));
    *(ushort4*)&Ls[cc][seg*4] = t4;
  }
  __syncthreads();
  for (int idx = tid; idx < 256*4; idx += 256) {
    int n = idx >> 2, seg = idx & 3;
    union { ushort_t u[8]; uint4 v; } pk;
    #pragma unroll
    for (int e = 0; e < 8; e++) pk.u[e] = Ls[seg*8 + e][n];
    *(uint4*)(xn_t + ((size_t)(bl*4096 + nt*256 + n))*256 + c0 + seg*8) = pk.v;
  }
}

// ------- fp32 -> bf16 weight convert, both weight tensors in one launch ----
__global__ __launch_bounds__(256)
void wconv2(const float* __restrict__ wq, const float* __restrict__ wp,
            ushort_t* __restrict__ oq, ushort_t* __restrict__ op) {
  int blk = blockIdx.x;            // 0-191: qkv (196608), 192-255: proj (65536)
  const float* w; ushort_t* o; int i;
  if (blk < 192) { w = wq; o = oq; i = blk*256 + threadIdx.x; }
  else           { w = wp; o = op; i = (blk-192)*256 + threadIdx.x; }
  float4 v = *(const float4*)(w + (size_t)i*4);
  *(ushort4*)(o + (size_t)i*4) = make_ushort4(f2bf(v.x), f2bf(v.y), f2bf(v.z), f2bf(v.w));
}

// ------- GEMM1: tile 128M x 64N. Q->q[tok][256] (scaled), K->k[tok][256],
//         V -> vt[b*4+h][d][tok] (transposed through LDS, one head/tile).
//         XCD-grouping swizzle: the 12 n-tiles sharing one A-panel land on
//         one XCD -> A reads become L2-hits.
__global__ __launch_bounds__(256)
void gemm_qkv(const ushort_t* __restrict__ A, const ushort_t* __restrict__ Bt,
              const float* __restrict__ bias, ushort_t* __restrict__ q,
              ushort_t* __restrict__ kbuf, ushort_t* __restrict__ vt,
              int b0, int cpx) {
  int L = blockIdx.x;
  int blk = (L & 7) * cpx + (L >> 3);   // grid = 8*cpx
  int nt = blk % 12, mt = blk / 12;
  int m0 = mt*128, n0 = nt*64;
  int tid = threadIdx.x;
  int wave = tid >> 6, lane = tid & 63, quad = lane >> 4, l16 = lane & 15;
  __shared__ ushort_t As[128][40];
  __shared__ ushort_t Bs[64][40];
  __shared__ ushort_t Lt[64][136];   // V transpose tile [d][tok]
  f32x4 acc[2][4];
  #pragma unroll
  for (int i = 0; i < 2; i++)
    #pragma unroll
    for (int j = 0; j < 4; j++) acc[i][j] = (f32x4){0.f,0.f,0.f,0.f};

  for (int k0 = 0; k0 < 256; k0 += 32) {
    #pragma unroll
    for (int i = tid; i < 512; i += 256) {
      int row = i >> 2, seg = i & 3;
      *(uint4*)&As[row][seg*8] = *(const uint4*)(A + (size_t)(m0+row)*256 + k0 + seg*8);
    }
    {
      int row = tid >> 2, seg = tid & 3;
      *(uint4*)&Bs[row][seg*8] = *(const uint4*)(Bt + (size_t)(n0+row)*256 + k0 + seg*8);
    }
    __syncthreads();
    bf16x8 af[2], bfr[4];
    #pragma unroll
    for (int t = 0; t < 2; t++) af[t]  = *(const bf16x8*)&As[wave*32 + t*16 + l16][quad*8];
    #pragma unroll
    for (int t = 0; t < 4; t++) bfr[t] = *(const bf16x8*)&Bs[t*16 + l16][quad*8];
    #pragma unroll
    for (int ti = 0; ti < 2; ti++)
      #pragma unroll
      for (int jn = 0; jn < 4; jn++)
        acc[ti][jn] = __builtin_amdgcn_mfma_f32_16x16x32_bf16(af[ti], bfr[jn], acc[ti][jn], 0, 0, 0);
    __syncthreads();
  }

  int region = nt >> 2;   // 0=Q (n<256), 1=K, 2=V
  if (region == 0) {
    #pragma unroll
    for (int jn = 0; jn < 4; jn++) {
      int n = n0 + jn*16 + l16;
      float bv = bias[n];
      #pragma unroll
      for (int ti = 0; ti < 2; ti++) {
        int mrow = m0 + wave*32 + ti*16 + quad*4;
        #pragma unroll
        for (int r = 0; r < 4; r++)
          q[(size_t)(b0*4096 + mrow + r)*256 + n] = f2bf((acc[ti][jn][r] + bv) * SCALE_Q);
      }
    }
  } else if (region == 1) {
    #pragma unroll
    for (int jn = 0; jn < 4; jn++) {
      int n = n0 + jn*16 + l16;
      float bv = bias[n];
      #pragma unroll
      for (int ti = 0; ti < 2; ti++) {
        int mrow = m0 + wave*32 + ti*16 + quad*4;
        #pragma unroll
        for (int r = 0; r < 4; r++)
          kbuf[(size_t)(b0*4096 + mrow + r)*256 + (n - 256)] = f2bf(acc[ti][jn][r] + bv);
      }
    }
  } else {
    int hh = nt - 8;                 // one head per 64-wide tile
    int b_loc = m0 >> 12;
    #pragma unroll
    for (int jn = 0; jn < 4; jn++) {
      int n = n0 + jn*16 + l16;
      float bv = bias[n];
      int drow = jn*16 + l16;        // d within head (0..63)
      #pragma unroll
      for (int ti = 0; ti < 2; ti++) {
        int tcol = wave*32 + ti*16 + quad*4;
        uint2 w;
        w.x = pack_rn(acc[ti][jn][0] + bv, acc[ti][jn][1] + bv);
        w.y = pack_rn(acc[ti][jn][2] + bv, acc[ti][jn][3] + bv);
        *(uint2*)&Lt[drow][tcol] = w;
      }
    }
    __syncthreads();
    size_t vb_ = ((size_t)((b0 + b_loc)*4 + hh)*64)*4096 + (size_t)(m0 & 4095);
    for (int idx = tid; idx < 1024; idx += 256) {
      int dd = idx >> 4, toff = (idx & 15)*8;
      *(uint4*)(vt + vb_ + (size_t)dd*4096 + toff) = *(const uint4*)&Lt[dd][toff];
    }
  }
}

// -------- flash attention v19: v18 + sched_group_barrier interleave map.
// v18 post-mortem: VALU-busy (1910cyc) + MFMA-busy (1140cyc) ~= elapsed
// (3350cyc) per window -> the pipes run SERIALLY. Phases are lockstep:
// QK/PV emit MFMA clusters (VALU idle), softmax emits exp/pack (MFMA
// idle); the compiler did not interleave them. v19 adds a T19-style
// emission map: K-reads, QK(s0) chain, 4x{1 MFMA(s1) + 11 VALU(SM0)},
// V-reads, 4x{1 MFMA(PV0) + 11 VALU(SM1)}, V-reads, PV1 cluster. A wave
// then issues VALU while its own MFMAs execute (separate pipes).
// Success signature: MfmaUtil AND VALUBusy rise together.
__global__ __launch_bounds__(256)
void attn(ushort_t* __restrict__ q, const ushort_t* __restrict__ k,
          const ushort_t* __restrict__ vt, int cpx) {
  int L = blockIdx.x;
  int blk = (L & 7) * cpx + (L >> 3);   // XCD-grouping remap (grid = 8*cpx)
  int it = blk & 31;
  int h  = (blk >> 5) & 3;
  int b  = blk >> 7;
  int i0 = it * 128;
  int tid = threadIdx.x;
  int wave = tid >> 6, lane = tid & 63;
  int q32 = lane & 31, hi = lane >> 5;

  __shared__ ushort_t Ks[2][64][72];   // [buf][key][d]  stride 144B (0-conflict)
  __shared__ ushort_t Vs[2][64][72];   // [buf][d][key]  stride 144B (0-conflict)

  const ushort_t* kbase = k + (size_t)(b*4096)*256 + h*64;
  const ushort_t* vbase = vt + (size_t)(b*4 + h)*64*4096;
  ushort_t* qrow = q + (size_t)(b*4096 + i0 + wave*32 + q32)*256 + h*64;

  // Q B-fragments: n = q32, k(d) = s*16 + hi*8 + e  (direct from global)
  bf16x8 qb0 = *(const bf16x8*)(qrow      + hi*8);
  bf16x8 qb1 = *(const bf16x8*)(qrow + 16 + hi*8);
  bf16x8 qb2 = *(const bf16x8*)(qrow + 32 + hi*8);
  bf16x8 qb3 = *(const bf16x8*)(qrow + 48 + hi*8);

  f32x16 bias_init;                // persistent C operand for first QK MFMA
  #pragma unroll
  for (int r = 0; r < 16; r++) bias_init[r] = -EXP_BIAS;

  f32x16 o_acc0, o_acc1;           // O^T frags (m = d blocks of 32, n = query)
  #pragma unroll
  for (int r = 0; r < 16; r++) { o_acc0[r] = 0.f; o_acc1[r] = 0.f; }
  float lsum = 0.f;                // per-lane row-sum (keys of this hi half)

  // staging: 256 threads; K tile 64 keys x 128B, V tile 64 d x 128B
  int srow = tid >> 2, scol = (tid & 3) * 16;
  const ushort_t* kp = kbase + (size_t)srow*256 + scol;
  const ushort_t* vp = vbase + (size_t)srow*4096 + scol;
  uint4 rk0, rk1, rv0, rv1;
  #define LOADK() { \
    rk0 = *(const uint4*)(kp); \
    rk1 = *(const uint4*)(kp + 8); \
    kp += 64*256; }
  #define WRITEK(BI) { \
    *(uint4*)&Ks[BI][srow][scol]     = rk0; \
    *(uint4*)&Ks[BI][srow][scol + 8] = rk1; }
  #define LOADV() { \
    rv0 = *(const uint4*)(vp); \
    rv1 = *(const uint4*)(vp + 8); \
    vp += 64; }
  #define WRITEV(BI) { \
    *(uint4*)&Vs[BI][srow][scol]     = rv0; \
    *(uint4*)&Vs[BI][srow][scol + 8] = rv1; }

  // softmax of one sub's scores: 16 exp2 + 15-add lsum tree + 8 pack + 4 swap
  #define SOFTMAX(S, PB0, PB1) \
    _Pragma("unroll") \
    for (int r = 0; r < 16; r++) S[r] = fast_exp2(S[r]); \
    lsum += ((((S[0]+S[1])+(S[2]+S[3])) + ((S[4]+S[5])+(S[6]+S[7]))) \
           + (((S[8]+S[9])+(S[10]+S[11])) + ((S[12]+S[13])+(S[14]+S[15])))); \
    { unsigned pkA = pack_trunc(S[0],  S[1]),  pkB = pack_trunc(S[2],  S[3]); \
      unsigned pkC = pack_trunc(S[4],  S[5]),  pkD = pack_trunc(S[6],  S[7]); \
      unsigned pkE = pack_trunc(S[8],  S[9]),  pkF = pack_trunc(S[10], S[11]); \
      unsigned pkG = pack_trunc(S[12], S[13]), pkH = pack_trunc(S[14], S[15]); \
      swap32(pkA, pkC); swap32(pkB, pkD); \
      swap32(pkE, pkG); swap32(pkF, pkH); \
      u32x4 w0_ = {pkA, pkB, pkC, pkD}; \
      u32x4 w1_ = {pkE, pkF, pkG, pkH}; \
      PB0 = __builtin_bit_cast(bf16x8, w0_); \
      PB1 = __builtin_bit_cast(bf16x8, w1_); }

  // one 64-key window: 2 interleaved 32-key subs.
  // QK C-layout: P[key = sub*32 + (r&3) + 8*(r>>2) + 4*hi][query q32].
  #define WINDOW(BI) { \
    bf16x8 k00 = *(const bf16x8*)&Ks[BI][q32     ][hi*8]; \
    bf16x8 k01 = *(const bf16x8*)&Ks[BI][q32     ][16 + hi*8]; \
    bf16x8 k02 = *(const bf16x8*)&Ks[BI][q32     ][32 + hi*8]; \
    bf16x8 k03 = *(const bf16x8*)&Ks[BI][q32     ][48 + hi*8]; \
    bf16x8 k10 = *(const bf16x8*)&Ks[BI][32 + q32][hi*8]; \
    bf16x8 k11 = *(const bf16x8*)&Ks[BI][32 + q32][16 + hi*8]; \
    bf16x8 k12 = *(const bf16x8*)&Ks[BI][32 + q32][32 + hi*8]; \
    bf16x8 k13 = *(const bf16x8*)&Ks[BI][32 + q32][48 + hi*8]; \
    __builtin_amdgcn_s_setprio(1); \
    f32x16 s0 = __builtin_amdgcn_mfma_f32_32x32x16_bf16(k00, qb0, bias_init, 0, 0, 0); \
    s0 = __builtin_amdgcn_mfma_f32_32x32x16_bf16(k01, qb1, s0, 0, 0, 0); \
    s0 = __builtin_amdgcn_mfma_f32_32x32x16_bf16(k02, qb2, s0, 0, 0, 0); \
    s0 = __builtin_amdgcn_mfma_f32_32x32x16_bf16(k03, qb3, s0, 0, 0, 0); \
    f32x16 s1 = __builtin_amdgcn_mfma_f32_32x32x16_bf16(k10, qb0, bias_init, 0, 0, 0); \
    s1 = __builtin_amdgcn_mfma_f32_32x32x16_bf16(k11, qb1, s1, 0, 0, 0); \
    s1 = __builtin_amdgcn_mfma_f32_32x32x16_bf16(k12, qb2, s1, 0, 0, 0); \
    s1 = __builtin_amdgcn_mfma_f32_32x32x16_bf16(k13, qb3, s1, 0, 0, 0); \
    bf16x8 pb00, pb01, pb10, pb11; \
    SOFTMAX(s0, pb00, pb01)   /* interleaved with s1's MFMAs via SGB map */ \
    { bf16x8 vb00 = *(const bf16x8*)&Vs[BI][q32     ][hi*8]; \
      bf16x8 vb01 = *(const bf16x8*)&Vs[BI][q32     ][16 + hi*8]; \
      bf16x8 vb10 = *(const bf16x8*)&Vs[BI][32 + q32][hi*8]; \
      bf16x8 vb11 = *(const bf16x8*)&Vs[BI][32 + q32][16 + hi*8]; \
      o_acc0 = __builtin_amdgcn_mfma_f32_32x32x16_bf16(vb00, pb00, o_acc0, 0, 0, 0); \
      o_acc0 = __builtin_amdgcn_mfma_f32_32x32x16_bf16(vb01, pb01, o_acc0, 0, 0, 0); \
      o_acc1 = __builtin_amdgcn_mfma_f32_32x32x16_bf16(vb10, pb00, o_acc1, 0, 0, 0); \
      o_acc1 = __builtin_amdgcn_mfma_f32_32x32x16_bf16(vb11, pb01, o_acc1, 0, 0, 0); } \
    SOFTMAX(s1, pb10, pb11)   /* interleaved with PV(sub0) MFMAs via SGB map */ \
    { bf16x8 vb00 = *(const bf16x8*)&Vs[BI][q32     ][32 + hi*8]; \
      bf16x8 vb01 = *(const bf16x8*)&Vs[BI][q32     ][48 + hi*8]; \
      bf16x8 vb10 = *(const bf16x8*)&Vs[BI][32 + q32][32 + hi*8]; \
      bf16x8 vb11 = *(const bf16x8*)&Vs[BI][32 + q32][48 + hi*8]; \
      o_acc0 = __builtin_amdgcn_mfma_f32_32x32x16_bf16(vb00, pb10, o_acc0, 0, 0, 0); \
      o_acc0 = __builtin_amdgcn_mfma_f32_32x32x16_bf16(vb01, pb11, o_acc0, 0, 0, 0); \
      o_acc1 = __builtin_amdgcn_mfma_f32_32x32x16_bf16(vb10, pb10, o_acc1, 0, 0, 0); \
      o_acc1 = __builtin_amdgcn_mfma_f32_32x32x16_bf16(vb11, pb11, o_acc1, 0, 0, 0); } \
    __builtin_amdgcn_s_setprio(0); \
    /* emission map (mask: MFMA=0x8 VALU=0x2 DS_READ=0x100): */ \
    SGB(0x100, 8);                       /* K-frag reads */ \
    SGB(0x8, 4);                         /* QK s0 chain */ \
    SGB(0x8, 1); SGB(0x2, 11);           /* s1 MFMA + SM0 slice */ \
    SGB(0x8, 1); SGB(0x2, 11); \
    SGB(0x8, 1); SGB(0x2, 11); \
    SGB(0x8, 1); SGB(0x2, 11); \
    SGB(0x100, 4);                       /* V0 reads */ \
    SGB(0x8, 1); SGB(0x2, 11);           /* PV0 MFMA + SM1 slice */ \
    SGB(0x8, 1); SGB(0x2, 11); \
    SGB(0x8, 1); SGB(0x2, 11); \
    SGB(0x8, 1); SGB(0x2, 11); \
    SGB(0x100, 4);                       /* V1 reads */ \
    SGB(0x8, 4);                         /* PV1 cluster */ \
  }

  LOADK(); LOADV(); WRITEK(0); WRITEV(0);
  __syncthreads();

  #pragma unroll 2
  for (int w = 0; w < 64; w++) {
    int cur = w & 1;
    if (w < 63) { LOADK(); LOADV(); }   // window w+1 -> regs, age across compute
    WINDOW(cur)
    if (w < 63) { WRITEK(cur ^ 1); WRITEV(cur ^ 1); }
    __syncthreads();                    // nxt written, cur reads done
  }
  #undef LOADK
  #undef LOADV
  #undef WRITEK
  #undef WRITEV
  #undef WINDOW
  #undef SOFTMAX

  // lane(l) holds sum over its hi-half keys; partner lane l^32 has the rest
  unsigned ua = __float_as_uint(lsum), ub = ua;
  swap32(ua, ub);
  float ltot = __uint_as_float(ua) + __uint_as_float(ub);
  float inv = 1.f / ltot;

  // O^T frag: n = q32 (row), d = dblk*32 + g*8 + hi*4 + r
  #pragma unroll
  for (int g = 0; g < 4; g++) {
    ushort4 u;
    u.x = f2bf(o_acc0[g*4+0]*inv); u.y = f2bf(o_acc0[g*4+1]*inv);
    u.z = f2bf(o_acc0[g*4+2]*inv); u.w = f2bf(o_acc0[g*4+3]*inv);
    *(ushort4*)(qrow + g*8 + hi*4) = u;
  }
  #pragma unroll
  for (int g = 0; g < 4; g++) {
    ushort4 u;
    u.x = f2bf(o_acc1[g*4+0]*inv); u.y = f2bf(o_acc1[g*4+1]*inv);
    u.z = f2bf(o_acc1[g*4+2]*inv); u.w = f2bf(o_acc1[g*4+3]*inv);
    *(ushort4*)(qrow + 32 + g*8 + hi*4) = u;
  }
}

// - GEMM2: tile 128M x 64N. out[col][o] = sum_c wp[o][c]*O[col][c]+bias+resid
// O lives in q buffer, stride 256.
__global__ __launch_bounds__(256)
void gemm_proj(const ushort_t* __restrict__ A,    // wproj_bf [256][256]
               const ushort_t* __restrict__ Bt,   // q (O) [*][256]
               const float* __restrict__ bias, const float* __restrict__ resid,
               float* __restrict__ out, int col_base) {
  int blk = blockIdx.x;            // nb*128 = mt(2) x nt(nb*64)
  int mt = blk & 1, nt = blk >> 1;
  int m0 = mt*128, n0 = nt*64;
  int tid = threadIdx.x;
  int wave = tid >> 6, lane = tid & 63, quad = lane >> 4, l16 = lane & 15;
  __shared__ ushort_t As[128][40];
  __shared__ ushort_t Bs[64][40];
  f32x4 acc[2][4];
  #pragma unroll
  for (int i = 0; i < 2; i++)
    #pragma unroll
    for (int j = 0; j < 4; j++) acc[i][j] = (f32x4){0.f,0.f,0.f,0.f};

  for (int k0 = 0; k0 < 256; k0 += 32) {
    #pragma unroll
    for (int i = tid; i < 512; i += 256) {
      int row = i >> 2, seg = i & 3;
      *(uint4*)&As[row][seg*8] = *(const uint4*)(A + (size_t)(m0+row)*256 + k0 + seg*8);
    }
    {
      int row = tid >> 2, seg = tid & 3;
      *(uint4*)&Bs[row][seg*8] = *(const uint4*)(Bt + (size_t)(n0+row)*256 + k0 + seg*8);
    }
    __syncthreads();
    bf16x8 af[2], bfr[4];
    #pragma unroll
    for (int t = 0; t < 2; t++) af[t]  = *(const bf16x8*)&As[wave*32 + t*16 + l16][quad*8];
    #pragma unroll
    for (int t = 0; t < 4; t++) bfr[t] = *(const bf16x8*)&Bs[t*16 + l16][quad*8];
    #pragma unroll
    for (int ti = 0; ti < 2; ti++)
      #pragma unroll
      for (int jn = 0; jn < 4; jn++)
        acc[ti][jn] = __builtin_amdgcn_mfma_f32_16x16x32_bf16(af[ti], bfr[jn], acc[ti][jn], 0, 0, 0);
    __syncthreads();
  }
  #pragma unroll
  for (int jn = 0; jn < 4; jn++) {
    int col = col_base + n0 + jn*16 + l16;
    int bb = col >> 12;
    int np = col & 4095;
    #pragma unroll
    for (int ti = 0; ti < 2; ti++) {
      int o = m0 + wave*32 + ti*16 + quad*4;
      #pragma unroll
      for (int r = 0; r < 4; r++) {
        int oo = o + r;
        size_t addr = ((size_t)(bb*256 + oo))*4096 + np;
        out[addr] = acc[ti][jn][r] + bias[oo] + resid[addr];
      }
    }
  }
}

extern "C" void kernel_launch(void* const* d_in, const int* in_sizes, int n_in,
                              void* d_out, int out_size, void* d_ws, size_t ws_size,
                              hipStream_t stream) {
  const float* x      = (const float*)d_in[0];
  const float* gamma  = (const float*)d_in[1];
  const float* beta   = (const float*)d_in[2];
  const float* w_qkv  = (const float*)d_in[3];
  const float* b_qkv  = (const float*)d_in[4];
  const float* w_proj = (const float*)d_in[5];
  const float* b_proj = (const float*)d_in[6];
  float* out = (float*)d_out;

  char* ws = (char*)d_ws;
  float2* partial  = (float2*)(ws + 1024);         // 2048 B
  ushort_t* wqkv_bf  = (ushort_t*)(ws + 4096);     // 393216 B
  ushort_t* wproj_bf = (ushort_t*)(ws + 397312);   // 131072 B
  char* big = ws + 528384;

  gn_stats1<<<dim3(256), dim3(256), 0, stream>>>(x, partial);
  wconv2<<<dim3(256), dim3(256), 0, stream>>>(w_qkv, w_proj, wqkv_bf, wproj_bf);

  // Full path: q 8.39M + k 8.39M + vt 8.39M + xn(nb=2) 4.19M = 29,888,512 B.
  if (ws_size >= (size_t)528384 + 3*(size_t)8388608 + (size_t)4194304) {
    ushort_t* q    = (ushort_t*)big;
    ushort_t* kbuf = (ushort_t*)(big + (size_t)8388608);
    ushort_t* vt   = (ushort_t*)(big + (size_t)16777216);
    ushort_t* xn   = (ushort_t*)(big + (size_t)25165824);
    for (int c = 0; c < 2; c++) {
      int b0 = c * 2;
      gn_apply_t<<<dim3(256), dim3(256), 0, stream>>>(x, partial, gamma, beta, xn, b0);
      gemm_qkv<<<dim3(768), dim3(256), 0, stream>>>(xn, wqkv_bf, b_qkv, q, kbuf, vt, b0, 96);
    }
    attn<<<dim3(512), dim3(256), 0, stream>>>(q, kbuf, vt, 64);
    gemm_proj<<<dim3(512), dim3(256), 0, stream>>>(wproj_bf, q, b_proj, x, out, 0);
  } else {
    // Per-batch fallback: 4 x 2.1M = 8.4M after fixed region.
    ushort_t* q_c  = (ushort_t*)big;
    ushort_t* k_c  = (ushort_t*)(big + (size_t)2097152);
    ushort_t* vt_c = (ushort_t*)(big + (size_t)4194304);
    ushort_t* xn_c = (ushort_t*)(big + (size_t)6291456);
    for (int b0 = 0; b0 < 4; b0++) {
      gn_apply_t<<<dim3(128), dim3(256), 0, stream>>>(x, partial, gamma, beta, xn_c, b0);
      gemm_qkv<<<dim3(384), dim3(256), 0, stream>>>(xn_c, wqkv_bf, b_qkv, q_c, k_c, vt_c, 0, 48);
      attn<<<dim3(128), dim3(256), 0, stream>>>(q_c, k_c, vt_c, 16);
      gemm_proj<<<dim3(128), dim3(256), 0, stream>>>(wproj_bf, q_c, b_proj, x, out, b0*4096);
    }
  }
}

// Round 18
// 208.810 us; speedup vs baseline: 1.0336x; 1.0336x over previous
//
#include <hip/hip_runtime.h>
#include <stdint.h>

typedef unsigned short ushort_t;
typedef __attribute__((ext_vector_type(8))) short bf16x8;   // 8 bf16 = 4 VGPRs
typedef __attribute__((ext_vector_type(4))) float f32x4;
typedef __attribute__((ext_vector_type(16))) float f32x16;
typedef __attribute__((ext_vector_type(4))) unsigned int u32x4;

__device__ __forceinline__ ushort_t f2bf(float f) {
  union { float f; unsigned u; } v; v.f = f;
  unsigned r = v.u + 0x7fffu + ((v.u >> 16) & 1u);
  return (ushort_t)(r >> 16);
}
__device__ __forceinline__ unsigned bfbits(float f) {
  union { float f; unsigned u; } v; v.f = f; return v.u;
}
// pack two floats' bf16 truncations: [hi.bf16 : lo.bf16]
__device__ __forceinline__ unsigned pack_trunc(float lo, float hi) {
#if __has_builtin(__builtin_amdgcn_perm)
  return __builtin_amdgcn_perm(bfbits(hi), bfbits(lo), 0x07060302u);
#else
  return (bfbits(lo) >> 16) | (bfbits(hi) & 0xffff0000u);
#endif
}
__device__ __forceinline__ unsigned pack_rn(float lo, float hi) {
  return (unsigned)f2bf(lo) | ((unsigned)f2bf(hi) << 16);
}
// v_permlane32_swap_b32: a.hi32lanes <-> b.lo32lanes (both updated)
__device__ __forceinline__ void swap32(unsigned &a, unsigned &b) {
#if __has_builtin(__builtin_amdgcn_permlane32_swap)
  auto r = __builtin_amdgcn_permlane32_swap(a, b, false, false);
  a = r[0]; b = r[1];
#else
  asm volatile("v_permlane32_swap_b32 %0, %1" : "+v"(a), "+v"(b));
#endif
}
// raw v_exp_f32 (1 instr): libm exp2f expands to a multi-instr fixup
// sequence without fast-math; our inputs are bounded so raw HW op is exact.
__device__ __forceinline__ float fast_exp2(float x) {
#if __has_builtin(__builtin_amdgcn_exp2f)
  return __builtin_amdgcn_exp2f(x);
#else
  float r; asm("v_exp_f32 %0, %1" : "=v"(r) : "v"(x)); return r;
#endif
}
// sched_group_barrier: compile-time instruction-interleave directive
#if __has_builtin(__builtin_amdgcn_sched_group_barrier)
#define SGB(mask, n) __builtin_amdgcn_sched_group_barrier(mask, n, 0)
#else
#define SGB(mask, n)
#endif

#define SCALE_Q 0.18033688011112042f   /* 0.125 * log2(e) */
#define EXP_BIAS 23.083109273961734f   /* 16 * log2(e) */

// ---- prep: blocks 0-255 = GroupNorm stats stage 1; 256-511 = wconv -------
__global__ __launch_bounds__(256)
void prep(const float* __restrict__ x, float2* __restrict__ partial,
          const float* __restrict__ wq, const float* __restrict__ wp,
          ushort_t* __restrict__ oq, ushort_t* __restrict__ op) {
  int blk = blockIdx.x, tid = threadIdx.x;
  if (blk < 256) {
    const float* base = x + (size_t)blk * 16384;
    float s = 0.f, ss = 0.f;
    for (int i = tid * 4; i < 16384; i += 1024) {
      float4 v = *(const float4*)(base + i);
      s  += v.x + v.y + v.z + v.w;
      ss += v.x*v.x + v.y*v.y + v.z*v.z + v.w*v.w;
    }
    __shared__ float rs[256], rss[256];
    rs[tid] = s; rss[tid] = ss;
    __syncthreads();
    for (int off = 128; off > 0; off >>= 1) {
      if (tid < off) { rs[tid] += rs[tid+off]; rss[tid] += rss[tid+off]; }
      __syncthreads();
    }
    if (tid == 0) partial[blk] = make_float2(rs[0], rss[0]);
  } else {
    int wb = blk - 256;              // 0-191: qkv (196608), 192-255: proj
    const float* w; ushort_t* o; int i;
    if (wb < 192) { w = wq; o = oq; i = wb*256 + tid; }
    else          { w = wp; o = op; i = (wb-192)*256 + tid; }
    float4 v = *(const float4*)(w + (size_t)i*4);
    *(ushort4*)(o + (size_t)i*4) = make_ushort4(f2bf(v.x), f2bf(v.y), f2bf(v.z), f2bf(v.w));
  }
}

// -- normalize+transpose: x[b][c][n] -> xn_t[(b-b0)*4096+n][c] (bf16 chunk) -
// gn_stats2 folded in: each block reduces its group's 8 partials itself.
__global__ __launch_bounds__(256)
void gn_apply_t(const float* __restrict__ x, const float2* __restrict__ partial,
                const float* __restrict__ gamma, const float* __restrict__ beta,
                ushort_t* __restrict__ xn_t, int b0) {
  int blk = blockIdx.x;            // nb*128 = bl x nt(16) x ct(8)
  int tid = threadIdx.x;
  int ct = blk & 7;
  int nt = (blk >> 3) & 15;
  int bl = blk >> 7;               // local batch in chunk
  int b  = b0 + bl;                // global batch
  int c0 = ct * 32;                // one 32-ch group per tile (group == ct)
  float s = 0.f, ss = 0.f;
  #pragma unroll
  for (int kk = 0; kk < 8; kk++) {
    float2 p = partial[(b*8 + ct)*8 + kk];
    s += p.x; ss += p.y;
  }
  float mean = s * (1.f/131072.f);
  float rstd = rsqrtf(ss * (1.f/131072.f) - mean*mean + 1e-5f);
  __shared__ ushort_t Ls[32][264];
  for (int idx = tid; idx < 32*64; idx += 256) {
    int cc = idx >> 6, seg = idx & 63;
    float ga = gamma[c0+cc], be = beta[c0+cc];
    float a = rstd * ga;
    float bb = be - mean * a;
    float4 v = *(const float4*)(x + ((size_t)(b*256 + c0 + cc))*4096 + nt*256 + seg*4);
    ushort4 t4 = make_ushort4(f2bf(v.x*a+bb), f2bf(v.y*a+bb), f2bf(v.z*a+bb), f2bf(v.w*a+bb));
    *(ushort4*)&Ls[cc][seg*4] = t4;
  }
  __syncthreads();
  for (int idx = tid; idx < 256*4; idx += 256) {
    int n = idx >> 2, seg = idx & 3;
    union { ushort_t u[8]; uint4 v; } pk;
    #pragma unroll
    for (int e = 0; e < 8; e++) pk.u[e] = Ls[seg*8 + e][n];
    *(uint4*)(xn_t + ((size_t)(bl*4096 + nt*256 + n))*256 + c0 + seg*8) = pk.v;
  }
}

// ------- GEMM1: tile 128M x 64N. Q->q[tok][256] (scaled), K->k[tok][256],
//         V -> vt[b*4+h][d][tok] (transposed through LDS, one head/tile).
//         XCD-grouping swizzle: the 12 n-tiles sharing one A-panel land on
//         one XCD -> A reads become L2-hits.
__global__ __launch_bounds__(256)
void gemm_qkv(const ushort_t* __restrict__ A, const ushort_t* __restrict__ Bt,
              const float* __restrict__ bias, ushort_t* __restrict__ q,
              ushort_t* __restrict__ kbuf, ushort_t* __restrict__ vt,
              int b0, int cpx) {
  int L = blockIdx.x;
  int blk = (L & 7) * cpx + (L >> 3);   // grid = 8*cpx
  int nt = blk % 12, mt = blk / 12;
  int m0 = mt*128, n0 = nt*64;
  int tid = threadIdx.x;
  int wave = tid >> 6, lane = tid & 63, quad = lane >> 4, l16 = lane & 15;
  __shared__ ushort_t As[128][40];
  __shared__ ushort_t Bs[64][40];
  __shared__ ushort_t Lt[64][136];   // V transpose tile [d][tok]
  f32x4 acc[2][4];
  #pragma unroll
  for (int i = 0; i < 2; i++)
    #pragma unroll
    for (int j = 0; j < 4; j++) acc[i][j] = (f32x4){0.f,0.f,0.f,0.f};

  for (int k0 = 0; k0 < 256; k0 += 32) {
    #pragma unroll
    for (int i = tid; i < 512; i += 256) {
      int row = i >> 2, seg = i & 3;
      *(uint4*)&As[row][seg*8] = *(const uint4*)(A + (size_t)(m0+row)*256 + k0 + seg*8);
    }
    {
      int row = tid >> 2, seg = tid & 3;
      *(uint4*)&Bs[row][seg*8] = *(const uint4*)(Bt + (size_t)(n0+row)*256 + k0 + seg*8);
    }
    __syncthreads();
    bf16x8 af[2], bfr[4];
    #pragma unroll
    for (int t = 0; t < 2; t++) af[t]  = *(const bf16x8*)&As[wave*32 + t*16 + l16][quad*8];
    #pragma unroll
    for (int t = 0; t < 4; t++) bfr[t] = *(const bf16x8*)&Bs[t*16 + l16][quad*8];
    #pragma unroll
    for (int ti = 0; ti < 2; ti++)
      #pragma unroll
      for (int jn = 0; jn < 4; jn++)
        acc[ti][jn] = __builtin_amdgcn_mfma_f32_16x16x32_bf16(af[ti], bfr[jn], acc[ti][jn], 0, 0, 0);
    __syncthreads();
  }

  int region = nt >> 2;   // 0=Q (n<256), 1=K, 2=V
  if (region == 0) {
    #pragma unroll
    for (int jn = 0; jn < 4; jn++) {
      int n = n0 + jn*16 + l16;
      float bv = bias[n];
      #pragma unroll
      for (int ti = 0; ti < 2; ti++) {
        int mrow = m0 + wave*32 + ti*16 + quad*4;
        #pragma unroll
        for (int r = 0; r < 4; r++)
          q[(size_t)(b0*4096 + mrow + r)*256 + n] = f2bf((acc[ti][jn][r] + bv) * SCALE_Q);
      }
    }
  } else if (region == 1) {
    #pragma unroll
    for (int jn = 0; jn < 4; jn++) {
      int n = n0 + jn*16 + l16;
      float bv = bias[n];
      #pragma unroll
      for (int ti = 0; ti < 2; ti++) {
        int mrow = m0 + wave*32 + ti*16 + quad*4;
        #pragma unroll
        for (int r = 0; r < 4; r++)
          kbuf[(size_t)(b0*4096 + mrow + r)*256 + (n - 256)] = f2bf(acc[ti][jn][r] + bv);
      }
    }
  } else {
    int hh = nt - 8;                 // one head per 64-wide tile
    int b_loc = m0 >> 12;
    #pragma unroll
    for (int jn = 0; jn < 4; jn++) {
      int n = n0 + jn*16 + l16;
      float bv = bias[n];
      int drow = jn*16 + l16;        // d within head (0..63)
      #pragma unroll
      for (int ti = 0; ti < 2; ti++) {
        int tcol = wave*32 + ti*16 + quad*4;
        uint2 w;
        w.x = pack_rn(acc[ti][jn][0] + bv, acc[ti][jn][1] + bv);
        w.y = pack_rn(acc[ti][jn][2] + bv, acc[ti][jn][3] + bv);
        *(uint2*)&Lt[drow][tcol] = w;
      }
    }
    __syncthreads();
    size_t vb_ = ((size_t)((b0 + b_loc)*4 + hh)*64)*4096 + (size_t)(m0 & 4095);
    for (int idx = tid; idx < 1024; idx += 256) {
      int dd = idx >> 4, toff = (idx & 15)*8;
      *(uint4*)(vt + vb_ + (size_t)dd*4096 + toff) = *(const uint4*)&Lt[dd][toff];
    }
  }
}

// -------- flash attention v19 (unchanged; best measured: 87.4us).
// 2-sub pipeline, 144B 0-conflict strides, fast_exp2, pointer-bump staging,
// XCD grouping, VALU lsum, SGB interleave map.
__global__ __launch_bounds__(256)
void attn(ushort_t* __restrict__ q, const ushort_t* __restrict__ k,
          const ushort_t* __restrict__ vt, int cpx) {
  int L = blockIdx.x;
  int blk = (L & 7) * cpx + (L >> 3);   // XCD-grouping remap (grid = 8*cpx)
  int it = blk & 31;
  int h  = (blk >> 5) & 3;
  int b  = blk >> 7;
  int i0 = it * 128;
  int tid = threadIdx.x;
  int wave = tid >> 6, lane = tid & 63;
  int q32 = lane & 31, hi = lane >> 5;

  __shared__ ushort_t Ks[2][64][72];   // [buf][key][d]  stride 144B (0-conflict)
  __shared__ ushort_t Vs[2][64][72];   // [buf][d][key]  stride 144B (0-conflict)

  const ushort_t* kbase = k + (size_t)(b*4096)*256 + h*64;
  const ushort_t* vbase = vt + (size_t)(b*4 + h)*64*4096;
  ushort_t* qrow = q + (size_t)(b*4096 + i0 + wave*32 + q32)*256 + h*64;

  // Q B-fragments: n = q32, k(d) = s*16 + hi*8 + e  (direct from global)
  bf16x8 qb0 = *(const bf16x8*)(qrow      + hi*8);
  bf16x8 qb1 = *(const bf16x8*)(qrow + 16 + hi*8);
  bf16x8 qb2 = *(const bf16x8*)(qrow + 32 + hi*8);
  bf16x8 qb3 = *(const bf16x8*)(qrow + 48 + hi*8);

  f32x16 bias_init;                // persistent C operand for first QK MFMA
  #pragma unroll
  for (int r = 0; r < 16; r++) bias_init[r] = -EXP_BIAS;

  f32x16 o_acc0, o_acc1;           // O^T frags (m = d blocks of 32, n = query)
  #pragma unroll
  for (int r = 0; r < 16; r++) { o_acc0[r] = 0.f; o_acc1[r] = 0.f; }
  float lsum = 0.f;                // per-lane row-sum (keys of this hi half)

  // staging: 256 threads; K tile 64 keys x 128B, V tile 64 d x 128B
  int srow = tid >> 2, scol = (tid & 3) * 16;
  const ushort_t* kp = kbase + (size_t)srow*256 + scol;
  const ushort_t* vp = vbase + (size_t)srow*4096 + scol;
  uint4 rk0, rk1, rv0, rv1;
  #define LOADK() { \
    rk0 = *(const uint4*)(kp); \
    rk1 = *(const uint4*)(kp + 8); \
    kp += 64*256; }
  #define WRITEK(BI) { \
    *(uint4*)&Ks[BI][srow][scol]     = rk0; \
    *(uint4*)&Ks[BI][srow][scol + 8] = rk1; }
  #define LOADV() { \
    rv0 = *(const uint4*)(vp); \
    rv1 = *(const uint4*)(vp + 8); \
    vp += 64; }
  #define WRITEV(BI) { \
    *(uint4*)&Vs[BI][srow][scol]     = rv0; \
    *(uint4*)&Vs[BI][srow][scol + 8] = rv1; }

  // softmax of one sub's scores: 16 exp2 + 15-add lsum tree + 8 pack + 4 swap
  #define SOFTMAX(S, PB0, PB1) \
    _Pragma("unroll") \
    for (int r = 0; r < 16; r++) S[r] = fast_exp2(S[r]); \
    lsum += ((((S[0]+S[1])+(S[2]+S[3])) + ((S[4]+S[5])+(S[6]+S[7]))) \
           + (((S[8]+S[9])+(S[10]+S[11])) + ((S[12]+S[13])+(S[14]+S[15])))); \
    { unsigned pkA = pack_trunc(S[0],  S[1]),  pkB = pack_trunc(S[2],  S[3]); \
      unsigned pkC = pack_trunc(S[4],  S[5]),  pkD = pack_trunc(S[6],  S[7]); \
      unsigned pkE = pack_trunc(S[8],  S[9]),  pkF = pack_trunc(S[10], S[11]); \
      unsigned pkG = pack_trunc(S[12], S[13]), pkH = pack_trunc(S[14], S[15]); \
      swap32(pkA, pkC); swap32(pkB, pkD); \
      swap32(pkE, pkG); swap32(pkF, pkH); \
      u32x4 w0_ = {pkA, pkB, pkC, pkD}; \
      u32x4 w1_ = {pkE, pkF, pkG, pkH}; \
      PB0 = __builtin_bit_cast(bf16x8, w0_); \
      PB1 = __builtin_bit_cast(bf16x8, w1_); }

  // one 64-key window: 2 interleaved 32-key subs.
  // QK C-layout: P[key = sub*32 + (r&3) + 8*(r>>2) + 4*hi][query q32].
  #define WINDOW(BI) { \
    bf16x8 k00 = *(const bf16x8*)&Ks[BI][q32     ][hi*8]; \
    bf16x8 k01 = *(const bf16x8*)&Ks[BI][q32     ][16 + hi*8]; \
    bf16x8 k02 = *(const bf16x8*)&Ks[BI][q32     ][32 + hi*8]; \
    bf16x8 k03 = *(const bf16x8*)&Ks[BI][q32     ][48 + hi*8]; \
    bf16x8 k10 = *(const bf16x8*)&Ks[BI][32 + q32][hi*8]; \
    bf16x8 k11 = *(const bf16x8*)&Ks[BI][32 + q32][16 + hi*8]; \
    bf16x8 k12 = *(const bf16x8*)&Ks[BI][32 + q32][32 + hi*8]; \
    bf16x8 k13 = *(const bf16x8*)&Ks[BI][32 + q32][48 + hi*8]; \
    __builtin_amdgcn_s_setprio(1); \
    f32x16 s0 = __builtin_amdgcn_mfma_f32_32x32x16_bf16(k00, qb0, bias_init, 0, 0, 0); \
    s0 = __builtin_amdgcn_mfma_f32_32x32x16_bf16(k01, qb1, s0, 0, 0, 0); \
    s0 = __builtin_amdgcn_mfma_f32_32x32x16_bf16(k02, qb2, s0, 0, 0, 0); \
    s0 = __builtin_amdgcn_mfma_f32_32x32x16_bf16(k03, qb3, s0, 0, 0, 0); \
    f32x16 s1 = __builtin_amdgcn_mfma_f32_32x32x16_bf16(k10, qb0, bias_init, 0, 0, 0); \
    s1 = __builtin_amdgcn_mfma_f32_32x32x16_bf16(k11, qb1, s1, 0, 0, 0); \
    s1 = __builtin_amdgcn_mfma_f32_32x32x16_bf16(k12, qb2, s1, 0, 0, 0); \
    s1 = __builtin_amdgcn_mfma_f32_32x32x16_bf16(k13, qb3, s1, 0, 0, 0); \
    bf16x8 pb00, pb01, pb10, pb11; \
    SOFTMAX(s0, pb00, pb01)   /* interleaved with s1's MFMAs via SGB map */ \
    { bf16x8 vb00 = *(const bf16x8*)&Vs[BI][q32     ][hi*8]; \
      bf16x8 vb01 = *(const bf16x8*)&Vs[BI][q32     ][16 + hi*8]; \
      bf16x8 vb10 = *(const bf16x8*)&Vs[BI][32 + q32][hi*8]; \
      bf16x8 vb11 = *(const bf16x8*)&Vs[BI][32 + q32][16 + hi*8]; \
      o_acc0 = __builtin_amdgcn_mfma_f32_32x32x16_bf16(vb00, pb00, o_acc0, 0, 0, 0); \
      o_acc0 = __builtin_amdgcn_mfma_f32_32x32x16_bf16(vb01, pb01, o_acc0, 0, 0, 0); \
      o_acc1 = __builtin_amdgcn_mfma_f32_32x32x16_bf16(vb10, pb00, o_acc1, 0, 0, 0); \
      o_acc1 = __builtin_amdgcn_mfma_f32_32x32x16_bf16(vb11, pb01, o_acc1, 0, 0, 0); } \
    SOFTMAX(s1, pb10, pb11)   /* interleaved with PV(sub0) MFMAs via SGB map */ \
    { bf16x8 vb00 = *(const bf16x8*)&Vs[BI][q32     ][32 + hi*8]; \
      bf16x8 vb01 = *(const bf16x8*)&Vs[BI][q32     ][48 + hi*8]; \
      bf16x8 vb10 = *(const bf16x8*)&Vs[BI][32 + q32][32 + hi*8]; \
      bf16x8 vb11 = *(const bf16x8*)&Vs[BI][32 + q32][48 + hi*8]; \
      o_acc0 = __builtin_amdgcn_mfma_f32_32x32x16_bf16(vb00, pb10, o_acc0, 0, 0, 0); \
      o_acc0 = __builtin_amdgcn_mfma_f32_32x32x16_bf16(vb01, pb11, o_acc0, 0, 0, 0); \
      o_acc1 = __builtin_amdgcn_mfma_f32_32x32x16_bf16(vb10, pb10, o_acc1, 0, 0, 0); \
      o_acc1 = __builtin_amdgcn_mfma_f32_32x32x16_bf16(vb11, pb11, o_acc1, 0, 0, 0); } \
    __builtin_amdgcn_s_setprio(0); \
    /* emission map (mask: MFMA=0x8 VALU=0x2 DS_READ=0x100): */ \
    SGB(0x100, 8);                       /* K-frag reads */ \
    SGB(0x8, 4);                         /* QK s0 chain */ \
    SGB(0x8, 1); SGB(0x2, 11);           /* s1 MFMA + SM0 slice */ \
    SGB(0x8, 1); SGB(0x2, 11); \
    SGB(0x8, 1); SGB(0x2, 11); \
    SGB(0x8, 1); SGB(0x2, 11); \
    SGB(0x100, 4);                       /* V0 reads */ \
    SGB(0x8, 1); SGB(0x2, 11);           /* PV0 MFMA + SM1 slice */ \
    SGB(0x8, 1); SGB(0x2, 11); \
    SGB(0x8, 1); SGB(0x2, 11); \
    SGB(0x8, 1); SGB(0x2, 11); \
    SGB(0x100, 4);                       /* V1 reads */ \
    SGB(0x8, 4);                         /* PV1 cluster */ \
  }

  LOADK(); LOADV(); WRITEK(0); WRITEV(0);
  __syncthreads();

  #pragma unroll 2
  for (int w = 0; w < 64; w++) {
    int cur = w & 1;
    if (w < 63) { LOADK(); LOADV(); }   // window w+1 -> regs, age across compute
    WINDOW(cur)
    if (w < 63) { WRITEK(cur ^ 1); WRITEV(cur ^ 1); }
    __syncthreads();                    // nxt written, cur reads done
  }
  #undef LOADK
  #undef LOADV
  #undef WRITEK
  #undef WRITEV
  #undef WINDOW
  #undef SOFTMAX

  // lane(l) holds sum over its hi-half keys; partner lane l^32 has the rest
  unsigned ua = __float_as_uint(lsum), ub = ua;
  swap32(ua, ub);
  float ltot = __uint_as_float(ua) + __uint_as_float(ub);
  float inv = 1.f / ltot;

  // O^T frag: n = q32 (row), d = dblk*32 + g*8 + hi*4 + r
  #pragma unroll
  for (int g = 0; g < 4; g++) {
    ushort4 u;
    u.x = f2bf(o_acc0[g*4+0]*inv); u.y = f2bf(o_acc0[g*4+1]*inv);
    u.z = f2bf(o_acc0[g*4+2]*inv); u.w = f2bf(o_acc0[g*4+3]*inv);
    *(ushort4*)(qrow + g*8 + hi*4) = u;
  }
  #pragma unroll
  for (int g = 0; g < 4; g++) {
    ushort4 u;
    u.x = f2bf(o_acc1[g*4+0]*inv); u.y = f2bf(o_acc1[g*4+1]*inv);
    u.z = f2bf(o_acc1[g*4+2]*inv); u.w = f2bf(o_acc1[g*4+3]*inv);
    *(ushort4*)(qrow + 32 + g*8 + hi*4) = u;
  }
}

// - GEMM2: tile 128M x 64N. out[col][o] = sum_c wp[o][c]*O[col][c]+bias+resid
// O lives in q buffer, stride 256.
__global__ __launch_bounds__(256)
void gemm_proj(const ushort_t* __restrict__ A,    // wproj_bf [256][256]
               const ushort_t* __restrict__ Bt,   // q (O) [*][256]
               const float* __restrict__ bias, const float* __restrict__ resid,
               float* __restrict__ out, int col_base) {
  int blk = blockIdx.x;            // nb*128 = mt(2) x nt(nb*64)
  int mt = blk & 1, nt = blk >> 1;
  int m0 = mt*128, n0 = nt*64;
  int tid = threadIdx.x;
  int wave = tid >> 6, lane = tid & 63, quad = lane >> 4, l16 = lane & 15;
  __shared__ ushort_t As[128][40];
  __shared__ ushort_t Bs[64][40];
  f32x4 acc[2][4];
  #pragma unroll
  for (int i = 0; i < 2; i++)
    #pragma unroll
    for (int j = 0; j < 4; j++) acc[i][j] = (f32x4){0.f,0.f,0.f,0.f};

  for (int k0 = 0; k0 < 256; k0 += 32) {
    #pragma unroll
    for (int i = tid; i < 512; i += 256) {
      int row = i >> 2, seg = i & 3;
      *(uint4*)&As[row][seg*8] = *(const uint4*)(A + (size_t)(m0+row)*256 + k0 + seg*8);
    }
    {
      int row = tid >> 2, seg = tid & 3;
      *(uint4*)&Bs[row][seg*8] = *(const uint4*)(Bt + (size_t)(n0+row)*256 + k0 + seg*8);
    }
    __syncthreads();
    bf16x8 af[2], bfr[4];
    #pragma unroll
    for (int t = 0; t < 2; t++) af[t]  = *(const bf16x8*)&As[wave*32 + t*16 + l16][quad*8];
    #pragma unroll
    for (int t = 0; t < 4; t++) bfr[t] = *(const bf16x8*)&Bs[t*16 + l16][quad*8];
    #pragma unroll
    for (int ti = 0; ti < 2; ti++)
      #pragma unroll
      for (int jn = 0; jn < 4; jn++)
        acc[ti][jn] = __builtin_amdgcn_mfma_f32_16x16x32_bf16(af[ti], bfr[jn], acc[ti][jn], 0, 0, 0);
    __syncthreads();
  }
  #pragma unroll
  for (int jn = 0; jn < 4; jn++) {
    int col = col_base + n0 + jn*16 + l16;
    int bb = col >> 12;
    int np = col & 4095;
    #pragma unroll
    for (int ti = 0; ti < 2; ti++) {
      int o = m0 + wave*32 + ti*16 + quad*4;
      #pragma unroll
      for (int r = 0; r < 4; r++) {
        int oo = o + r;
        size_t addr = ((size_t)(bb*256 + oo))*4096 + np;
        out[addr] = acc[ti][jn][r] + bias[oo] + resid[addr];
      }
    }
  }
}

extern "C" void kernel_launch(void* const* d_in, const int* in_sizes, int n_in,
                              void* d_out, int out_size, void* d_ws, size_t ws_size,
                              hipStream_t stream) {
  const float* x      = (const float*)d_in[0];
  const float* gamma  = (const float*)d_in[1];
  const float* beta   = (const float*)d_in[2];
  const float* w_qkv  = (const float*)d_in[3];
  const float* b_qkv  = (const float*)d_in[4];
  const float* w_proj = (const float*)d_in[5];
  const float* b_proj = (const float*)d_in[6];
  float* out = (float*)d_out;

  char* ws = (char*)d_ws;
  float2* partial  = (float2*)(ws + 1024);         // 2048 B
  ushort_t* wqkv_bf  = (ushort_t*)(ws + 4096);     // 393216 B
  ushort_t* wproj_bf = (ushort_t*)(ws + 397312);   // 131072 B
  char* big = ws + 528384;

  prep<<<dim3(512), dim3(256), 0, stream>>>(x, partial, w_qkv, w_proj, wqkv_bf, wproj_bf);

  // Single-chunk path: q 8.39M + k 8.39M + vt 8.39M + xn(4b) 8.39M = 34.08MB
  if (ws_size >= (size_t)528384 + 4*(size_t)8388608) {
    ushort_t* q    = (ushort_t*)big;
    ushort_t* kbuf = (ushort_t*)(big + (size_t)8388608);
    ushort_t* vt   = (ushort_t*)(big + (size_t)16777216);
    ushort_t* xn   = (ushort_t*)(big + (size_t)25165824);
    gn_apply_t<<<dim3(512), dim3(256), 0, stream>>>(x, partial, gamma, beta, xn, 0);
    gemm_qkv<<<dim3(1536), dim3(256), 0, stream>>>(xn, wqkv_bf, b_qkv, q, kbuf, vt, 0, 192);
    attn<<<dim3(512), dim3(256), 0, stream>>>(q, kbuf, vt, 64);
    gemm_proj<<<dim3(512), dim3(256), 0, stream>>>(wproj_bf, q, b_proj, x, out, 0);
  } else if (ws_size >= (size_t)528384 + 3*(size_t)8388608 + (size_t)4194304) {
    // Two-chunk path: xn(nb=2) 4.19M.
    ushort_t* q    = (ushort_t*)big;
    ushort_t* kbuf = (ushort_t*)(big + (size_t)8388608);
    ushort_t* vt   = (ushort_t*)(big + (size_t)16777216);
    ushort_t* xn   = (ushort_t*)(big + (size_t)25165824);
    for (int c = 0; c < 2; c++) {
      int b0 = c * 2;
      gn_apply_t<<<dim3(256), dim3(256), 0, stream>>>(x, partial, gamma, beta, xn, b0);
      gemm_qkv<<<dim3(768), dim3(256), 0, stream>>>(xn, wqkv_bf, b_qkv, q, kbuf, vt, b0, 96);
    }
    attn<<<dim3(512), dim3(256), 0, stream>>>(q, kbuf, vt, 64);
    gemm_proj<<<dim3(512), dim3(256), 0, stream>>>(wproj_bf, q, b_proj, x, out, 0);
  } else {
    // Per-batch fallback: 4 x 2.1M = 8.4M after fixed region.
    ushort_t* q_c  = (ushort_t*)big;
    ushort_t* k_c  = (ushort_t*)(big + (size_t)2097152);
    ushort_t* vt_c = (ushort_t*)(big + (size_t)4194304);
    ushort_t* xn_c = (ushort_t*)(big + (size_t)6291456);
    for (int b0 = 0; b0 < 4; b0++) {
      gn_apply_t<<<dim3(128), dim3(256), 0, stream>>>(x, partial, gamma, beta, xn_c, b0);
      gemm_qkv<<<dim3(384), dim3(256), 0, stream>>>(xn_c, wqkv_bf, b_qkv, q_c, k_c, vt_c, 0, 48);
      attn<<<dim3(128), dim3(256), 0, stream>>>(q_c, k_c, vt_c, 16);
      gemm_proj<<<dim3(128), dim3(256), 0, stream>>>(wproj_bf, q_c, b_proj, x, out, b0*4096);
    }
  }
}

// Round 19
// 207.027 us; speedup vs baseline: 1.0425x; 1.0086x over previous
//
#include <hip/hip_runtime.h>
#include <stdint.h>

typedef unsigned short ushort_t;
typedef __attribute__((ext_vector_type(8))) short bf16x8;   // 8 bf16 = 4 VGPRs
typedef __attribute__((ext_vector_type(4))) float f32x4;
typedef __attribute__((ext_vector_type(16))) float f32x16;
typedef __attribute__((ext_vector_type(4))) unsigned int u32x4;

__device__ __forceinline__ ushort_t f2bf(float f) {
  union { float f; unsigned u; } v; v.f = f;
  unsigned r = v.u + 0x7fffu + ((v.u >> 16) & 1u);
  return (ushort_t)(r >> 16);
}
__device__ __forceinline__ unsigned bfbits(float f) {
  union { float f; unsigned u; } v; v.f = f; return v.u;
}
// pack two floats' bf16 truncations: [hi.bf16 : lo.bf16]
__device__ __forceinline__ unsigned pack_trunc(float lo, float hi) {
#if __has_builtin(__builtin_amdgcn_perm)
  return __builtin_amdgcn_perm(bfbits(hi), bfbits(lo), 0x07060302u);
#else
  return (bfbits(lo) >> 16) | (bfbits(hi) & 0xffff0000u);
#endif
}
__device__ __forceinline__ unsigned pack_rn(float lo, float hi) {
  return (unsigned)f2bf(lo) | ((unsigned)f2bf(hi) << 16);
}
// v_permlane32_swap_b32: a.hi32lanes <-> b.lo32lanes (both updated)
__device__ __forceinline__ void swap32(unsigned &a, unsigned &b) {
#if __has_builtin(__builtin_amdgcn_permlane32_swap)
  auto r = __builtin_amdgcn_permlane32_swap(a, b, false, false);
  a = r[0]; b = r[1];
#else
  asm volatile("v_permlane32_swap_b32 %0, %1" : "+v"(a), "+v"(b));
#endif
}
// raw v_exp_f32 (1 instr): libm exp2f expands to a multi-instr fixup
// sequence without fast-math; our inputs are bounded so raw HW op is exact.
__device__ __forceinline__ float fast_exp2(float x) {
#if __has_builtin(__builtin_amdgcn_exp2f)
  return __builtin_amdgcn_exp2f(x);
#else
  float r; asm("v_exp_f32 %0, %1" : "=v"(r) : "v"(x)); return r;
#endif
}
// sched_group_barrier: compile-time instruction-interleave directive
#if __has_builtin(__builtin_amdgcn_sched_group_barrier)
#define SGB(mask, n) __builtin_amdgcn_sched_group_barrier(mask, n, 0)
#else
#define SGB(mask, n)
#endif

#define SCALE_Q 0.18033688011112042f   /* 0.125 * log2(e) */
#define EXP_BIAS 23.083109273961734f   /* 16 * log2(e) */

// ---- prep: blocks 0-255 = GroupNorm stats stage 1; 256-511 = wconv -------
__global__ __launch_bounds__(256)
void prep(const float* __restrict__ x, float2* __restrict__ partial,
          const float* __restrict__ wq, const float* __restrict__ wp,
          ushort_t* __restrict__ oq, ushort_t* __restrict__ op) {
  int blk = blockIdx.x, tid = threadIdx.x;
  if (blk < 256) {
    const float* base = x + (size_t)blk * 16384;
    float s = 0.f, ss = 0.f;
    for (int i = tid * 4; i < 16384; i += 1024) {
      float4 v = *(const float4*)(base + i);
      s  += v.x + v.y + v.z + v.w;
      ss += v.x*v.x + v.y*v.y + v.z*v.z + v.w*v.w;
    }
    __shared__ float rs[256], rss[256];
    rs[tid] = s; rss[tid] = ss;
    __syncthreads();
    for (int off = 128; off > 0; off >>= 1) {
      if (tid < off) { rs[tid] += rs[tid+off]; rss[tid] += rss[tid+off]; }
      __syncthreads();
    }
    if (tid == 0) partial[blk] = make_float2(rs[0], rss[0]);
  } else {
    int wb = blk - 256;              // 0-191: qkv (196608), 192-255: proj
    const float* w; ushort_t* o; int i;
    if (wb < 192) { w = wq; o = oq; i = wb*256 + tid; }
    else          { w = wp; o = op; i = (wb-192)*256 + tid; }
    float4 v = *(const float4*)(w + (size_t)i*4);
    *(ushort4*)(o + (size_t)i*4) = make_ushort4(f2bf(v.x), f2bf(v.y), f2bf(v.z), f2bf(v.w));
  }
}

// -- normalize+transpose: x[b][c][n] -> xn_t[(b-b0)*4096+n][c] (bf16 chunk) -
// gn_stats2 folded in: each block reduces its group's 8 partials itself.
__global__ __launch_bounds__(256)
void gn_apply_t(const float* __restrict__ x, const float2* __restrict__ partial,
                const float* __restrict__ gamma, const float* __restrict__ beta,
                ushort_t* __restrict__ xn_t, int b0) {
  int blk = blockIdx.x;            // nb*128 = bl x nt(16) x ct(8)
  int tid = threadIdx.x;
  int ct = blk & 7;
  int nt = (blk >> 3) & 15;
  int bl = blk >> 7;               // local batch in chunk
  int b  = b0 + bl;                // global batch
  int c0 = ct * 32;                // one 32-ch group per tile (group == ct)
  float s = 0.f, ss = 0.f;
  #pragma unroll
  for (int kk = 0; kk < 8; kk++) {
    float2 p = partial[(b*8 + ct)*8 + kk];
    s += p.x; ss += p.y;
  }
  float mean = s * (1.f/131072.f);
  float rstd = rsqrtf(ss * (1.f/131072.f) - mean*mean + 1e-5f);
  __shared__ ushort_t Ls[32][264];
  for (int idx = tid; idx < 32*64; idx += 256) {
    int cc = idx >> 6, seg = idx & 63;
    float ga = gamma[c0+cc], be = beta[c0+cc];
    float a = rstd * ga;
    float bb = be - mean * a;
    float4 v = *(const float4*)(x + ((size_t)(b*256 + c0 + cc))*4096 + nt*256 + seg*4);
    ushort4 t4 = make_ushort4(f2bf(v.x*a+bb), f2bf(v.y*a+bb), f2bf(v.z*a+bb), f2bf(v.w*a+bb));
    *(ushort4*)&Ls[cc][seg*4] = t4;
  }
  __syncthreads();
  for (int idx = tid; idx < 256*4; idx += 256) {
    int n = idx >> 2, seg = idx & 3;
    union { ushort_t u[8]; uint4 v; } pk;
    #pragma unroll
    for (int e = 0; e < 8; e++) pk.u[e] = Ls[seg*8 + e][n];
    *(uint4*)(xn_t + ((size_t)(bl*4096 + nt*256 + n))*256 + c0 + seg*8) = pk.v;
  }
}

// ------- GEMM1: tile 128M x 64N. Q->q[tok][256] (scaled), K->k[tok][256],
//         V -> vt[b*4+h][d][tok] (transposed through LDS, one head/tile).
//         XCD-grouping swizzle: the 12 n-tiles sharing one A-panel land on
//         one XCD -> A reads become L2-hits.
__global__ __launch_bounds__(256)
void gemm_qkv(const ushort_t* __restrict__ A, const ushort_t* __restrict__ Bt,
              const float* __restrict__ bias, ushort_t* __restrict__ q,
              ushort_t* __restrict__ kbuf, ushort_t* __restrict__ vt,
              int b0, int cpx) {
  int L = blockIdx.x;
  int blk = (L & 7) * cpx + (L >> 3);   // grid = 8*cpx
  int nt = blk % 12, mt = blk / 12;
  int m0 = mt*128, n0 = nt*64;
  int tid = threadIdx.x;
  int wave = tid >> 6, lane = tid & 63, quad = lane >> 4, l16 = lane & 15;
  __shared__ ushort_t As[128][40];
  __shared__ ushort_t Bs[64][40];
  __shared__ ushort_t Lt[64][136];   // V transpose tile [d][tok]
  f32x4 acc[2][4];
  #pragma unroll
  for (int i = 0; i < 2; i++)
    #pragma unroll
    for (int j = 0; j < 4; j++) acc[i][j] = (f32x4){0.f,0.f,0.f,0.f};

  for (int k0 = 0; k0 < 256; k0 += 32) {
    #pragma unroll
    for (int i = tid; i < 512; i += 256) {
      int row = i >> 2, seg = i & 3;
      *(uint4*)&As[row][seg*8] = *(const uint4*)(A + (size_t)(m0+row)*256 + k0 + seg*8);
    }
    {
      int row = tid >> 2, seg = tid & 3;
      *(uint4*)&Bs[row][seg*8] = *(const uint4*)(Bt + (size_t)(n0+row)*256 + k0 + seg*8);
    }
    __syncthreads();
    bf16x8 af[2], bfr[4];
    #pragma unroll
    for (int t = 0; t < 2; t++) af[t]  = *(const bf16x8*)&As[wave*32 + t*16 + l16][quad*8];
    #pragma unroll
    for (int t = 0; t < 4; t++) bfr[t] = *(const bf16x8*)&Bs[t*16 + l16][quad*8];
    #pragma unroll
    for (int ti = 0; ti < 2; ti++)
      #pragma unroll
      for (int jn = 0; jn < 4; jn++)
        acc[ti][jn] = __builtin_amdgcn_mfma_f32_16x16x32_bf16(af[ti], bfr[jn], acc[ti][jn], 0, 0, 0);
    __syncthreads();
  }

  int region = nt >> 2;   // 0=Q (n<256), 1=K, 2=V
  if (region == 0) {
    #pragma unroll
    for (int jn = 0; jn < 4; jn++) {
      int n = n0 + jn*16 + l16;
      float bv = bias[n];
      #pragma unroll
      for (int ti = 0; ti < 2; ti++) {
        int mrow = m0 + wave*32 + ti*16 + quad*4;
        #pragma unroll
        for (int r = 0; r < 4; r++)
          q[(size_t)(b0*4096 + mrow + r)*256 + n] = f2bf((acc[ti][jn][r] + bv) * SCALE_Q);
      }
    }
  } else if (region == 1) {
    #pragma unroll
    for (int jn = 0; jn < 4; jn++) {
      int n = n0 + jn*16 + l16;
      float bv = bias[n];
      #pragma unroll
      for (int ti = 0; ti < 2; ti++) {
        int mrow = m0 + wave*32 + ti*16 + quad*4;
        #pragma unroll
        for (int r = 0; r < 4; r++)
          kbuf[(size_t)(b0*4096 + mrow + r)*256 + (n - 256)] = f2bf(acc[ti][jn][r] + bv);
      }
    }
  } else {
    int hh = nt - 8;                 // one head per 64-wide tile
    int b_loc = m0 >> 12;
    #pragma unroll
    for (int jn = 0; jn < 4; jn++) {
      int n = n0 + jn*16 + l16;
      float bv = bias[n];
      int drow = jn*16 + l16;        // d within head (0..63)
      #pragma unroll
      for (int ti = 0; ti < 2; ti++) {
        int tcol = wave*32 + ti*16 + quad*4;
        uint2 w;
        w.x = pack_rn(acc[ti][jn][0] + bv, acc[ti][jn][1] + bv);
        w.y = pack_rn(acc[ti][jn][2] + bv, acc[ti][jn][3] + bv);
        *(uint2*)&Lt[drow][tcol] = w;
      }
    }
    __syncthreads();
    size_t vb_ = ((size_t)((b0 + b_loc)*4 + hh)*64)*4096 + (size_t)(m0 & 4095);
    for (int idx = tid; idx < 1024; idx += 256) {
      int dd = idx >> 4, toff = (idx & 15)*8;
      *(uint4*)(vt + vb_ + (size_t)dd*4096 + toff) = *(const uint4*)&Lt[dd][toff];
    }
  }
}

// -------- flash attention v19 (unchanged; best measured: 87.4-89.1us).
// 2-sub pipeline, 144B 0-conflict strides, fast_exp2, pointer-bump staging,
// XCD grouping, VALU lsum, SGB interleave map.
__global__ __launch_bounds__(256)
void attn(ushort_t* __restrict__ q, const ushort_t* __restrict__ k,
          const ushort_t* __restrict__ vt, int cpx) {
  int L = blockIdx.x;
  int blk = (L & 7) * cpx + (L >> 3);   // XCD-grouping remap (grid = 8*cpx)
  int it = blk & 31;
  int h  = (blk >> 5) & 3;
  int b  = blk >> 7;
  int i0 = it * 128;
  int tid = threadIdx.x;
  int wave = tid >> 6, lane = tid & 63;
  int q32 = lane & 31, hi = lane >> 5;

  __shared__ ushort_t Ks[2][64][72];   // [buf][key][d]  stride 144B (0-conflict)
  __shared__ ushort_t Vs[2][64][72];   // [buf][d][key]  stride 144B (0-conflict)

  const ushort_t* kbase = k + (size_t)(b*4096)*256 + h*64;
  const ushort_t* vbase = vt + (size_t)(b*4 + h)*64*4096;
  ushort_t* qrow = q + (size_t)(b*4096 + i0 + wave*32 + q32)*256 + h*64;

  // Q B-fragments: n = q32, k(d) = s*16 + hi*8 + e  (direct from global)
  bf16x8 qb0 = *(const bf16x8*)(qrow      + hi*8);
  bf16x8 qb1 = *(const bf16x8*)(qrow + 16 + hi*8);
  bf16x8 qb2 = *(const bf16x8*)(qrow + 32 + hi*8);
  bf16x8 qb3 = *(const bf16x8*)(qrow + 48 + hi*8);

  f32x16 bias_init;                // persistent C operand for first QK MFMA
  #pragma unroll
  for (int r = 0; r < 16; r++) bias_init[r] = -EXP_BIAS;

  f32x16 o_acc0, o_acc1;           // O^T frags (m = d blocks of 32, n = query)
  #pragma unroll
  for (int r = 0; r < 16; r++) { o_acc0[r] = 0.f; o_acc1[r] = 0.f; }
  float lsum = 0.f;                // per-lane row-sum (keys of this hi half)

  // staging: 256 threads; K tile 64 keys x 128B, V tile 64 d x 128B
  int srow = tid >> 2, scol = (tid & 3) * 16;
  const ushort_t* kp = kbase + (size_t)srow*256 + scol;
  const ushort_t* vp = vbase + (size_t)srow*4096 + scol;
  uint4 rk0, rk1, rv0, rv1;
  #define LOADK() { \
    rk0 = *(const uint4*)(kp); \
    rk1 = *(const uint4*)(kp + 8); \
    kp += 64*256; }
  #define WRITEK(BI) { \
    *(uint4*)&Ks[BI][srow][scol]     = rk0; \
    *(uint4*)&Ks[BI][srow][scol + 8] = rk1; }
  #define LOADV() { \
    rv0 = *(const uint4*)(vp); \
    rv1 = *(const uint4*)(vp + 8); \
    vp += 64; }
  #define WRITEV(BI) { \
    *(uint4*)&Vs[BI][srow][scol]     = rv0; \
    *(uint4*)&Vs[BI][srow][scol + 8] = rv1; }

  // softmax of one sub's scores: 16 exp2 + 15-add lsum tree + 8 pack + 4 swap
  #define SOFTMAX(S, PB0, PB1) \
    _Pragma("unroll") \
    for (int r = 0; r < 16; r++) S[r] = fast_exp2(S[r]); \
    lsum += ((((S[0]+S[1])+(S[2]+S[3])) + ((S[4]+S[5])+(S[6]+S[7]))) \
           + (((S[8]+S[9])+(S[10]+S[11])) + ((S[12]+S[13])+(S[14]+S[15])))); \
    { unsigned pkA = pack_trunc(S[0],  S[1]),  pkB = pack_trunc(S[2],  S[3]); \
      unsigned pkC = pack_trunc(S[4],  S[5]),  pkD = pack_trunc(S[6],  S[7]); \
      unsigned pkE = pack_trunc(S[8],  S[9]),  pkF = pack_trunc(S[10], S[11]); \
      unsigned pkG = pack_trunc(S[12], S[13]), pkH = pack_trunc(S[14], S[15]); \
      swap32(pkA, pkC); swap32(pkB, pkD); \
      swap32(pkE, pkG); swap32(pkF, pkH); \
      u32x4 w0_ = {pkA, pkB, pkC, pkD}; \
      u32x4 w1_ = {pkE, pkF, pkG, pkH}; \
      PB0 = __builtin_bit_cast(bf16x8, w0_); \
      PB1 = __builtin_bit_cast(bf16x8, w1_); }

  // one 64-key window: 2 interleaved 32-key subs.
  // QK C-layout: P[key = sub*32 + (r&3) + 8*(r>>2) + 4*hi][query q32].
  #define WINDOW(BI) { \
    bf16x8 k00 = *(const bf16x8*)&Ks[BI][q32     ][hi*8]; \
    bf16x8 k01 = *(const bf16x8*)&Ks[BI][q32     ][16 + hi*8]; \
    bf16x8 k02 = *(const bf16x8*)&Ks[BI][q32     ][32 + hi*8]; \
    bf16x8 k03 = *(const bf16x8*)&Ks[BI][q32     ][48 + hi*8]; \
    bf16x8 k10 = *(const bf16x8*)&Ks[BI][32 + q32][hi*8]; \
    bf16x8 k11 = *(const bf16x8*)&Ks[BI][32 + q32][16 + hi*8]; \
    bf16x8 k12 = *(const bf16x8*)&Ks[BI][32 + q32][32 + hi*8]; \
    bf16x8 k13 = *(const bf16x8*)&Ks[BI][32 + q32][48 + hi*8]; \
    __builtin_amdgcn_s_setprio(1); \
    f32x16 s0 = __builtin_amdgcn_mfma_f32_32x32x16_bf16(k00, qb0, bias_init, 0, 0, 0); \
    s0 = __builtin_amdgcn_mfma_f32_32x32x16_bf16(k01, qb1, s0, 0, 0, 0); \
    s0 = __builtin_amdgcn_mfma_f32_32x32x16_bf16(k02, qb2, s0, 0, 0, 0); \
    s0 = __builtin_amdgcn_mfma_f32_32x32x16_bf16(k03, qb3, s0, 0, 0, 0); \
    f32x16 s1 = __builtin_amdgcn_mfma_f32_32x32x16_bf16(k10, qb0, bias_init, 0, 0, 0); \
    s1 = __builtin_amdgcn_mfma_f32_32x32x16_bf16(k11, qb1, s1, 0, 0, 0); \
    s1 = __builtin_amdgcn_mfma_f32_32x32x16_bf16(k12, qb2, s1, 0, 0, 0); \
    s1 = __builtin_amdgcn_mfma_f32_32x32x16_bf16(k13, qb3, s1, 0, 0, 0); \
    bf16x8 pb00, pb01, pb10, pb11; \
    SOFTMAX(s0, pb00, pb01)   /* interleaved with s1's MFMAs via SGB map */ \
    { bf16x8 vb00 = *(const bf16x8*)&Vs[BI][q32     ][hi*8]; \
      bf16x8 vb01 = *(const bf16x8*)&Vs[BI][q32     ][16 + hi*8]; \
      bf16x8 vb10 = *(const bf16x8*)&Vs[BI][32 + q32][hi*8]; \
      bf16x8 vb11 = *(const bf16x8*)&Vs[BI][32 + q32][16 + hi*8]; \
      o_acc0 = __builtin_amdgcn_mfma_f32_32x32x16_bf16(vb00, pb00, o_acc0, 0, 0, 0); \
      o_acc0 = __builtin_amdgcn_mfma_f32_32x32x16_bf16(vb01, pb01, o_acc0, 0, 0, 0); \
      o_acc1 = __builtin_amdgcn_mfma_f32_32x32x16_bf16(vb10, pb00, o_acc1, 0, 0, 0); \
      o_acc1 = __builtin_amdgcn_mfma_f32_32x32x16_bf16(vb11, pb01, o_acc1, 0, 0, 0); } \
    SOFTMAX(s1, pb10, pb11)   /* interleaved with PV(sub0) MFMAs via SGB map */ \
    { bf16x8 vb00 = *(const bf16x8*)&Vs[BI][q32     ][32 + hi*8]; \
      bf16x8 vb01 = *(const bf16x8*)&Vs[BI][q32     ][48 + hi*8]; \
      bf16x8 vb10 = *(const bf16x8*)&Vs[BI][32 + q32][32 + hi*8]; \
      bf16x8 vb11 = *(const bf16x8*)&Vs[BI][32 + q32][48 + hi*8]; \
      o_acc0 = __builtin_amdgcn_mfma_f32_32x32x16_bf16(vb00, pb10, o_acc0, 0, 0, 0); \
      o_acc0 = __builtin_amdgcn_mfma_f32_32x32x16_bf16(vb01, pb11, o_acc0, 0, 0, 0); \
      o_acc1 = __builtin_amdgcn_mfma_f32_32x32x16_bf16(vb10, pb10, o_acc1, 0, 0, 0); \
      o_acc1 = __builtin_amdgcn_mfma_f32_32x32x16_bf16(vb11, pb11, o_acc1, 0, 0, 0); } \
    __builtin_amdgcn_s_setprio(0); \
    /* emission map (mask: MFMA=0x8 VALU=0x2 DS_READ=0x100): */ \
    SGB(0x100, 8);                       /* K-frag reads */ \
    SGB(0x8, 4);                         /* QK s0 chain */ \
    SGB(0x8, 1); SGB(0x2, 11);           /* s1 MFMA + SM0 slice */ \
    SGB(0x8, 1); SGB(0x2, 11); \
    SGB(0x8, 1); SGB(0x2, 11); \
    SGB(0x8, 1); SGB(0x2, 11); \
    SGB(0x100, 4);                       /* V0 reads */ \
    SGB(0x8, 1); SGB(0x2, 11);           /* PV0 MFMA + SM1 slice */ \
    SGB(0x8, 1); SGB(0x2, 11); \
    SGB(0x8, 1); SGB(0x2, 11); \
    SGB(0x8, 1); SGB(0x2, 11); \
    SGB(0x100, 4);                       /* V1 reads */ \
    SGB(0x8, 4);                         /* PV1 cluster */ \
  }

  LOADK(); LOADV(); WRITEK(0); WRITEV(0);
  __syncthreads();

  #pragma unroll 2
  for (int w = 0; w < 64; w++) {
    int cur = w & 1;
    if (w < 63) { LOADK(); LOADV(); }   // window w+1 -> regs, age across compute
    WINDOW(cur)
    if (w < 63) { WRITEK(cur ^ 1); WRITEV(cur ^ 1); }
    __syncthreads();                    // nxt written, cur reads done
  }
  #undef LOADK
  #undef LOADV
  #undef WRITEK
  #undef WRITEV
  #undef WINDOW
  #undef SOFTMAX

  // lane(l) holds sum over its hi-half keys; partner lane l^32 has the rest
  unsigned ua = __float_as_uint(lsum), ub = ua;
  swap32(ua, ub);
  float ltot = __uint_as_float(ua) + __uint_as_float(ub);
  float inv = 1.f / ltot;

  // O^T frag: n = q32 (row), d = dblk*32 + g*8 + hi*4 + r
  #pragma unroll
  for (int g = 0; g < 4; g++) {
    ushort4 u;
    u.x = f2bf(o_acc0[g*4+0]*inv); u.y = f2bf(o_acc0[g*4+1]*inv);
    u.z = f2bf(o_acc0[g*4+2]*inv); u.w = f2bf(o_acc0[g*4+3]*inv);
    *(ushort4*)(qrow + g*8 + hi*4) = u;
  }
  #pragma unroll
  for (int g = 0; g < 4; g++) {
    ushort4 u;
    u.x = f2bf(o_acc1[g*4+0]*inv); u.y = f2bf(o_acc1[g*4+1]*inv);
    u.z = f2bf(o_acc1[g*4+2]*inv); u.w = f2bf(o_acc1[g*4+3]*inv);
    *(ushort4*)(qrow + 32 + g*8 + hi*4) = u;
  }
}

// - GEMM2: tile 128M x 64N. out[col][o] = sum_c wp[o][c]*O[col][c]+bias+resid
// O lives in q buffer, stride 256. XCD-grouping swizzle: block pairs
// (mt=0/1) sharing one B-panel land on the same XCD -> B reads L2-hit.
__global__ __launch_bounds__(256)
void gemm_proj(const ushort_t* __restrict__ A,    // wproj_bf [256][256]
               const ushort_t* __restrict__ Bt,   // q (O) [*][256]
               const float* __restrict__ bias, const float* __restrict__ resid,
               float* __restrict__ out, int col_base, int cpx) {
  int L = blockIdx.x;
  int blk = (L & 7) * cpx + (L >> 3);   // grid = 8*cpx
  int mt = blk & 1, nt = blk >> 1;
  int m0 = mt*128, n0 = nt*64;
  int tid = threadIdx.x;
  int wave = tid >> 6, lane = tid & 63, quad = lane >> 4, l16 = lane & 15;
  __shared__ ushort_t As[128][40];
  __shared__ ushort_t Bs[64][40];
  f32x4 acc[2][4];
  #pragma unroll
  for (int i = 0; i < 2; i++)
    #pragma unroll
    for (int j = 0; j < 4; j++) acc[i][j] = (f32x4){0.f,0.f,0.f,0.f};

  for (int k0 = 0; k0 < 256; k0 += 32) {
    #pragma unroll
    for (int i = tid; i < 512; i += 256) {
      int row = i >> 2, seg = i & 3;
      *(uint4*)&As[row][seg*8] = *(const uint4*)(A + (size_t)(m0+row)*256 + k0 + seg*8);
    }
    {
      int row = tid >> 2, seg = tid & 3;
      *(uint4*)&Bs[row][seg*8] = *(const uint4*)(Bt + (size_t)(n0+row)*256 + k0 + seg*8);
    }
    __syncthreads();
    bf16x8 af[2], bfr[4];
    #pragma unroll
    for (int t = 0; t < 2; t++) af[t]  = *(const bf16x8*)&As[wave*32 + t*16 + l16][quad*8];
    #pragma unroll
    for (int t = 0; t < 4; t++) bfr[t] = *(const bf16x8*)&Bs[t*16 + l16][quad*8];
    #pragma unroll
    for (int ti = 0; ti < 2; ti++)
      #pragma unroll
      for (int jn = 0; jn < 4; jn++)
        acc[ti][jn] = __builtin_amdgcn_mfma_f32_16x16x32_bf16(af[ti], bfr[jn], acc[ti][jn], 0, 0, 0);
    __syncthreads();
  }
  #pragma unroll
  for (int jn = 0; jn < 4; jn++) {
    int col = col_base + n0 + jn*16 + l16;
    int bb = col >> 12;
    int np = col & 4095;
    #pragma unroll
    for (int ti = 0; ti < 2; ti++) {
      int o = m0 + wave*32 + ti*16 + quad*4;
      #pragma unroll
      for (int r = 0; r < 4; r++) {
        int oo = o + r;
        size_t addr = ((size_t)(bb*256 + oo))*4096 + np;
        out[addr] = acc[ti][jn][r] + bias[oo] + resid[addr];
      }
    }
  }
}

extern "C" void kernel_launch(void* const* d_in, const int* in_sizes, int n_in,
                              void* d_out, int out_size, void* d_ws, size_t ws_size,
                              hipStream_t stream) {
  const float* x      = (const float*)d_in[0];
  const float* gamma  = (const float*)d_in[1];
  const float* beta   = (const float*)d_in[2];
  const float* w_qkv  = (const float*)d_in[3];
  const float* b_qkv  = (const float*)d_in[4];
  const float* w_proj = (const float*)d_in[5];
  const float* b_proj = (const float*)d_in[6];
  float* out = (float*)d_out;

  char* ws = (char*)d_ws;
  float2* partial  = (float2*)(ws + 1024);         // 2048 B
  ushort_t* wqkv_bf  = (ushort_t*)(ws + 4096);     // 393216 B
  ushort_t* wproj_bf = (ushort_t*)(ws + 397312);   // 131072 B
  char* big = ws + 528384;

  prep<<<dim3(512), dim3(256), 0, stream>>>(x, partial, w_qkv, w_proj, wqkv_bf, wproj_bf);

  // Single-chunk path: q 8.39M + k 8.39M + vt 8.39M + xn(4b) 8.39M = 34.08MB
  if (ws_size >= (size_t)528384 + 4*(size_t)8388608) {
    ushort_t* q    = (ushort_t*)big;
    ushort_t* kbuf = (ushort_t*)(big + (size_t)8388608);
    ushort_t* vt   = (ushort_t*)(big + (size_t)16777216);
    ushort_t* xn   = (ushort_t*)(big + (size_t)25165824);
    gn_apply_t<<<dim3(512), dim3(256), 0, stream>>>(x, partial, gamma, beta, xn, 0);
    gemm_qkv<<<dim3(1536), dim3(256), 0, stream>>>(xn, wqkv_bf, b_qkv, q, kbuf, vt, 0, 192);
    attn<<<dim3(512), dim3(256), 0, stream>>>(q, kbuf, vt, 64);
    gemm_proj<<<dim3(512), dim3(256), 0, stream>>>(wproj_bf, q, b_proj, x, out, 0, 64);
  } else if (ws_size >= (size_t)528384 + 3*(size_t)8388608 + (size_t)4194304) {
    // Two-chunk path: xn(nb=2) 4.19M.
    ushort_t* q    = (ushort_t*)big;
    ushort_t* kbuf = (ushort_t*)(big + (size_t)8388608);
    ushort_t* vt   = (ushort_t*)(big + (size_t)16777216);
    ushort_t* xn   = (ushort_t*)(big + (size_t)25165824);
    for (int c = 0; c < 2; c++) {
      int b0 = c * 2;
      gn_apply_t<<<dim3(256), dim3(256), 0, stream>>>(x, partial, gamma, beta, xn, b0);
      gemm_qkv<<<dim3(768), dim3(256), 0, stream>>>(xn, wqkv_bf, b_qkv, q, kbuf, vt, b0, 96);
    }
    attn<<<dim3(512), dim3(256), 0, stream>>>(q, kbuf, vt, 64);
    gemm_proj<<<dim3(512), dim3(256), 0, stream>>>(wproj_bf, q, b_proj, x, out, 0, 64);
  } else {
    // Per-batch fallback: 4 x 2.1M = 8.4M after fixed region.
    ushort_t* q_c  = (ushort_t*)big;
    ushort_t* k_c  = (ushort_t*)(big + (size_t)2097152);
    ushort_t* vt_c = (ushort_t*)(big + (size_t)4194304);
    ushort_t* xn_c = (ushort_t*)(big + (size_t)6291456);
    for (int b0 = 0; b0 < 4; b0++) {
      gn_apply_t<<<dim3(128), dim3(256), 0, stream>>>(x, partial, gamma, beta, xn_c, b0);
      gemm_qkv<<<dim3(384), dim3(256), 0, stream>>>(xn_c, wqkv_bf, b_qkv, q_c, k_c, vt_c, 0, 48);
      attn<<<dim3(128), dim3(256), 0, stream>>>(q_c, k_c, vt_c, 16);
      gemm_proj<<<dim3(128), dim3(256), 0, stream>>>(wproj_bf, q_c, b_proj, x, out, b0*4096, 16);
    }
  }
}